// Round 1
// baseline (281.177 us; speedup 1.0000x reference)
//
#include <hip/hip_runtime.h>
#include <math.h>

// Trittention forward: B=2,H=8,S=192,D=64, fp32 in/out.
// scores[q,t,s] = sum_h q[h]*k1[t,h]*k2[s,h]; softmax over flat (t,s);
// z = (P/suma) contracted with v1 over t and v2 over s; lse = m + log(suma).
// Key identity: z[d] = (sum_t At[t] v1[t,d] + sum_s As[s] v2[s,d]) / suma,
// with At/As the row/col marginals of the unnormalized p.

#define SS 192
#define DD 64
#define NTHREADS 512   // 8 waves

__launch_bounds__(NTHREADS, 2)
__global__ void tritt_fwd(const float* __restrict__ qg,
                          const float* __restrict__ k1g,
                          const float* __restrict__ k2g,
                          const float* __restrict__ v1g,
                          const float* __restrict__ v2g,
                          float* __restrict__ zg,
                          float* __restrict__ lseg) {
    // W and K2 tiles: 192 rows x 64 floats, stored as 16 chunks of float4 per
    // row, chunk c stored at position c ^ (row & 15)  (bank-conflict swizzle).
    __shared__ float4 wl[SS * 16];
    __shared__ float4 k2l[SS * 16];
    __shared__ float At[SS];
    __shared__ float As[SS];
    __shared__ float zsh[DD];
    __shared__ float redm[8];
    __shared__ float reds[8];
    __shared__ float sum_sh;

    const int tid = threadIdx.x;
    const int bid = blockIdx.x;           // (b*H + n)*S + q
    const int head = bid / SS;
    const size_t hb = (size_t)head * SS * DD;

    if (tid < SS) At[tid] = 0.f;
    else if (tid < 2 * SS) As[tid - SS] = 0.f;
    else if (tid < 2 * SS + DD) zsh[tid - 2 * SS] = 0.f;

    // ---- stage W = q*k1 (elementwise over h) and k2 into LDS (swizzled) ----
    const float4* k1v = (const float4*)(k1g + hb);
    const float4* k2v = (const float4*)(k2g + hb);
    const float4* qv  = (const float4*)(qg + (size_t)bid * DD);
    #pragma unroll
    for (int it = 0; it < (SS * 16) / NTHREADS; ++it) {
        int f = tid + it * NTHREADS;      // float4 index, 0..3071
        int t = f >> 4;                   // row
        int c = f & 15;                   // chunk within row (constant per thread)
        int cs = c ^ (t & 15);
        float4 a  = k1v[f];
        float4 qq = qv[c];
        a.x *= qq.x; a.y *= qq.y; a.z *= qq.z; a.w *= qq.w;
        wl[t * 16 + cs]  = a;
        k2l[t * 16 + cs] = k2v[f];
    }
    __syncthreads();

    // ---- score GEMM: scores = W @ k2^T, 192x192, K=64, reg tile 12x6 ----
    const int tx = tid & 31;              // s-tile lane
    const int ty = tid >> 5;              // t-tile lane, 0..15

    float acc[12][6];
    #pragma unroll
    for (int i = 0; i < 12; ++i)
        #pragma unroll
        for (int j = 0; j < 6; ++j) acc[i][j] = 0.f;

    const int txm = tx & 15;
    for (int hq = 0; hq < 16; ++hq) {
        float4 kv[6];
        #pragma unroll
        for (int j = 0; j < 6; ++j)
            kv[j] = k2l[(tx + 32 * j) * 16 + (hq ^ txm)];
        float4 wv[12];
        #pragma unroll
        for (int i = 0; i < 12; ++i)
            wv[i] = wl[(ty + 16 * i) * 16 + (hq ^ ty)];
        #pragma unroll
        for (int i = 0; i < 12; ++i)
            #pragma unroll
            for (int j = 0; j < 6; ++j) {
                float a = acc[i][j];
                a = fmaf(wv[i].x, kv[j].x, a);
                a = fmaf(wv[i].y, kv[j].y, a);
                a = fmaf(wv[i].z, kv[j].z, a);
                a = fmaf(wv[i].w, kv[j].w, a);
                acc[i][j] = a;
            }
    }

    // ---- exact block max over all 36864 scores (they all live in regs) ----
    float lm = -1e30f;
    #pragma unroll
    for (int i = 0; i < 12; ++i)
        #pragma unroll
        for (int j = 0; j < 6; ++j) lm = fmaxf(lm, acc[i][j]);
    #pragma unroll
    for (int off = 32; off > 0; off >>= 1)
        lm = fmaxf(lm, __shfl_xor(lm, off, 64));
    if ((tid & 63) == 0) redm[tid >> 6] = lm;
    __syncthreads();
    if (tid == 0) {
        float m = redm[0];
        #pragma unroll
        for (int w = 1; w < 8; ++w) m = fmaxf(m, redm[w]);
        redm[0] = m;
    }
    __syncthreads();
    const float bm = redm[0];

    // ---- exp + marginals ----
    float colp[6] = {0.f, 0.f, 0.f, 0.f, 0.f, 0.f};
    float lsum = 0.f;
    #pragma unroll
    for (int i = 0; i < 12; ++i) {
        float rp = 0.f;
        #pragma unroll
        for (int j = 0; j < 6; ++j) {
            float p = __expf(acc[i][j] - bm);
            rp += p;
            colp[j] += p;
        }
        lsum += rp;
        // reduce row partial across the 32 tx lanes (stays within wave half)
        #pragma unroll
        for (int off = 16; off > 0; off >>= 1)
            rp += __shfl_xor(rp, off, 64);
        if (tx == 0) At[ty + 16 * i] = rp;   // unique writer, deterministic
    }
    #pragma unroll
    for (int j = 0; j < 6; ++j)
        atomicAdd(&As[tx + 32 * j], colp[j]);

    // block-wide sum (deterministic tree)
    #pragma unroll
    for (int off = 32; off > 0; off >>= 1)
        lsum += __shfl_xor(lsum, off, 64);
    if ((tid & 63) == 0) reds[tid >> 6] = lsum;
    __syncthreads();
    if (tid == 0) {
        float s = 0.f;
        #pragma unroll
        for (int w = 0; w < 8; ++w) s += reds[w];
        sum_sh = s;
    }
    __syncthreads();

    // ---- epilogue: z[d] = (sum_t At v1 + sum_s As v2) / suma ----
    const int d = tid & 63;
    const int g = tid >> 6;               // 0..7, each covers 24 t-rows
    const float* v1p = v1g + hb;
    const float* v2p = v2g + hb;
    float zp = 0.f;
    #pragma unroll
    for (int r = 0; r < 24; ++r) {
        int t = g * 24 + r;
        zp = fmaf(At[t], v1p[t * DD + d], zp);
        zp = fmaf(As[t], v2p[t * DD + d], zp);
    }
    atomicAdd(&zsh[d], zp);
    __syncthreads();

    const float suma = sum_sh;
    if (tid < DD) zg[(size_t)bid * DD + tid] = zsh[tid] / suma;
    if (tid == 0) lseg[bid] = bm + logf(suma);
}

extern "C" void kernel_launch(void* const* d_in, const int* in_sizes, int n_in,
                              void* d_out, int out_size, void* d_ws, size_t ws_size,
                              hipStream_t stream) {
    const float* q  = (const float*)d_in[0];
    const float* k1 = (const float*)d_in[1];
    const float* k2 = (const float*)d_in[2];
    const float* v1 = (const float*)d_in[3];
    const float* v2 = (const float*)d_in[4];
    float* out = (float*)d_out;

    const int nq = in_sizes[0] / DD;      // B*H*S = 3072
    float* zout   = out;
    float* lseout = out + (size_t)nq * DD;

    dim3 grid(nq), block(NTHREADS);
    hipLaunchKernelGGL(tritt_fwd, grid, block, 0, stream,
                       q, k1, k2, v1, v2, zout, lseout);
}

// Round 2
// 230.359 us; speedup vs baseline: 1.2206x; 1.2206x over previous
//
#include <hip/hip_runtime.h>
#include <math.h>

// Trittention forward: B=2,H=8,S=192,D=64, fp32 in/out.
// scores[q,t,s] = sum_h q[h]*k1[t,h]*k2[s,h]  ==  (W @ k2^T) with W = q (.) k1
// softmax over flat (t,s); z = (sum_t At v1 + sum_s As v2)/suma via marginals.
// Round 2: score GEMM on MFMA (bf16 inputs, fp32 accum). LDS 100KB->51KB
// so 3 blocks/CU; LDS reads drop 2304->144 b128 per block.

#define SS 192
#define DD 64
#define NT 512   // 8 waves: 2 (t) x 4 (s) wave grid

typedef __attribute__((ext_vector_type(8))) short bf16x8;
typedef __attribute__((ext_vector_type(4))) float f32x4;

static __device__ __forceinline__ unsigned short f2bf(float x) {
    union { float f; unsigned u; } v; v.f = x;
    unsigned u = v.u;
    return (unsigned short)((u + 0x7fffu + ((u >> 16) & 1u)) >> 16);  // RNE
}

__launch_bounds__(NT, 6)
__global__ void tritt_fwd(const float* __restrict__ qg,
                          const float* __restrict__ k1g,
                          const float* __restrict__ k2g,
                          const float* __restrict__ v1g,
                          const float* __restrict__ v2g,
                          float* __restrict__ zg,
                          float* __restrict__ lseg) {
    // bf16 tiles, row = 64 bf16 = 8 chunks of 16B; chunk c stored at c^(r&7).
    __shared__ uint4 wl[SS * 8];
    __shared__ uint4 k2l[SS * 8];
    __shared__ float At[SS];
    __shared__ float As[SS];
    __shared__ float zsh[DD];
    __shared__ float redm[8];
    __shared__ float reds[8];
    __shared__ float sum_sh;

    const int tid = threadIdx.x;
    const int bid = blockIdx.x;           // (b*H + n)*S + q
    const int head = bid / SS;
    const size_t hb = (size_t)head * SS * DD;

    if (tid < SS) At[tid] = 0.f;
    else if (tid < 2 * SS) As[tid - SS] = 0.f;
    else if (tid < 2 * SS + DD) zsh[tid - 2 * SS] = 0.f;

    // ---- stage W = q*k1 and k2 into LDS as bf16 (swizzled 16B chunks) ----
    const float4* k1v = (const float4*)(k1g + hb);
    const float4* k2v = (const float4*)(k2g + hb);
    const float4* qv  = (const float4*)(qg + (size_t)bid * DD);
    #pragma unroll
    for (int it = 0; it < (SS * 8) / NT; ++it) {   // 3 iters
        int f8 = tid + it * NT;            // 16B-chunk id, 0..1535
        int r = f8 >> 3;                   // row
        int c = f8 & 7;                    // chunk within row
        int idx = r * 8 + (c ^ (r & 7));
        float4 a0 = k1v[2 * f8], a1 = k1v[2 * f8 + 1];
        float4 q0 = qv[2 * c],   q1 = qv[2 * c + 1];
        uint4 w;
        w.x = (unsigned)f2bf(a0.x * q0.x) | ((unsigned)f2bf(a0.y * q0.y) << 16);
        w.y = (unsigned)f2bf(a0.z * q0.z) | ((unsigned)f2bf(a0.w * q0.w) << 16);
        w.z = (unsigned)f2bf(a1.x * q1.x) | ((unsigned)f2bf(a1.y * q1.y) << 16);
        w.w = (unsigned)f2bf(a1.z * q1.z) | ((unsigned)f2bf(a1.w * q1.w) << 16);
        wl[idx] = w;
        float4 b0 = k2v[2 * f8], b1 = k2v[2 * f8 + 1];
        uint4 kk;
        kk.x = (unsigned)f2bf(b0.x) | ((unsigned)f2bf(b0.y) << 16);
        kk.y = (unsigned)f2bf(b0.z) | ((unsigned)f2bf(b0.w) << 16);
        kk.z = (unsigned)f2bf(b1.x) | ((unsigned)f2bf(b1.y) << 16);
        kk.w = (unsigned)f2bf(b1.z) | ((unsigned)f2bf(b1.w) << 16);
        k2l[idx] = kk;
    }
    __syncthreads();

    // ---- score GEMM on MFMA: 192x192, K=64. Wave (wt,ws) owns 96x48. ----
    const int lane = tid & 63;
    const int wid  = tid >> 6;
    const int wt   = wid >> 2;            // 0..1
    const int ws   = wid & 3;             // 0..3
    const int lrow = lane & 15;
    const int lk   = lane >> 4;           // 0..3 (k-group)

    f32x4 acc[6][3];
    #pragma unroll
    for (int i = 0; i < 6; ++i)
        #pragma unroll
        for (int j = 0; j < 3; ++j)
            acc[i][j] = (f32x4){0.f, 0.f, 0.f, 0.f};

    #pragma unroll
    for (int ks = 0; ks < 2; ++ks) {
        bf16x8 bfr[3];
        #pragma unroll
        for (int j = 0; j < 3; ++j) {
            int srow = ws * 48 + j * 16 + lrow;
            bfr[j] = *(const bf16x8*)&k2l[srow * 8 + ((ks * 4 + lk) ^ (srow & 7))];
        }
        bf16x8 afr[6];
        #pragma unroll
        for (int i = 0; i < 6; ++i) {
            int trow = wt * 96 + i * 16 + lrow;
            afr[i] = *(const bf16x8*)&wl[trow * 8 + ((ks * 4 + lk) ^ (trow & 7))];
        }
        #pragma unroll
        for (int i = 0; i < 6; ++i)
            #pragma unroll
            for (int j = 0; j < 3; ++j)
                acc[i][j] = __builtin_amdgcn_mfma_f32_16x16x32_bf16(
                    afr[i], bfr[j], acc[i][j], 0, 0, 0);
    }
    // D mapping: col(s) = lane&15, row(t) = (lane>>4)*4 + reg.

    // ---- exact block max (all 36864 scores live in registers) ----
    float lm = -1e30f;
    #pragma unroll
    for (int i = 0; i < 6; ++i)
        #pragma unroll
        for (int j = 0; j < 3; ++j)
            #pragma unroll
            for (int r = 0; r < 4; ++r) lm = fmaxf(lm, acc[i][j][r]);
    #pragma unroll
    for (int off = 1; off < 64; off <<= 1)
        lm = fmaxf(lm, __shfl_xor(lm, off, 64));
    if (lane == 0) redm[wid] = lm;
    __syncthreads();
    if (tid == 0) {
        float m = redm[0];
        #pragma unroll
        for (int w = 1; w < 8; ++w) m = fmaxf(m, redm[w]);
        redm[0] = m;
    }
    __syncthreads();
    const float bm = redm[0];

    // ---- exp + marginals ----
    float colp[3] = {0.f, 0.f, 0.f};
    float lsum = 0.f;
    #pragma unroll
    for (int i = 0; i < 6; ++i) {
        float rs[4] = {0.f, 0.f, 0.f, 0.f};
        #pragma unroll
        for (int j = 0; j < 3; ++j)
            #pragma unroll
            for (int r = 0; r < 4; ++r) {
                float p = __expf(acc[i][j][r] - bm);
                rs[r] += p;
                colp[j] += p;
                lsum += p;
            }
        #pragma unroll
        for (int r = 0; r < 4; ++r) {
            float v = rs[r];
            v += __shfl_xor(v, 1, 64);
            v += __shfl_xor(v, 2, 64);
            v += __shfl_xor(v, 4, 64);
            v += __shfl_xor(v, 8, 64);
            if (lrow == 0)
                atomicAdd(&At[wt * 96 + i * 16 + lk * 4 + r], v);
        }
    }
    #pragma unroll
    for (int j = 0; j < 3; ++j) {
        float v = colp[j];
        v += __shfl_xor(v, 16, 64);
        v += __shfl_xor(v, 32, 64);
        if (lane < 16)
            atomicAdd(&As[ws * 48 + j * 16 + lane], v);
    }
    #pragma unroll
    for (int off = 1; off < 64; off <<= 1)
        lsum += __shfl_xor(lsum, off, 64);
    if (lane == 0) reds[wid] = lsum;
    __syncthreads();
    if (tid == 0) {
        float s = 0.f;
        #pragma unroll
        for (int w = 0; w < 8; ++w) s += reds[w];
        sum_sh = s;
    }
    __syncthreads();

    // ---- epilogue: z[d] = (sum_t At v1 + sum_s As v2) / suma ----
    const int d = tid & 63;
    const int g = tid >> 6;               // 0..7, each covers 24 rows
    const float* v1p = v1g + hb;
    const float* v2p = v2g + hb;
    float zp = 0.f;
    #pragma unroll
    for (int r = 0; r < 24; ++r) {
        int t = g * 24 + r;
        zp = fmaf(At[t], v1p[t * DD + d], zp);
        zp = fmaf(As[t], v2p[t * DD + d], zp);
    }
    atomicAdd(&zsh[d], zp);
    __syncthreads();

    const float suma = sum_sh;
    if (tid < DD) zg[(size_t)bid * DD + tid] = zsh[tid] / suma;
    if (tid == 0) lseg[bid] = bm + logf(suma);
}

extern "C" void kernel_launch(void* const* d_in, const int* in_sizes, int n_in,
                              void* d_out, int out_size, void* d_ws, size_t ws_size,
                              hipStream_t stream) {
    const float* q  = (const float*)d_in[0];
    const float* k1 = (const float*)d_in[1];
    const float* k2 = (const float*)d_in[2];
    const float* v1 = (const float*)d_in[3];
    const float* v2 = (const float*)d_in[4];
    float* out = (float*)d_out;

    const int nq = in_sizes[0] / DD;      // B*H*S = 3072
    float* zout   = out;
    float* lseout = out + (size_t)nq * DD;

    dim3 grid(nq), block(NT);
    hipLaunchKernelGGL(tritt_fwd, grid, block, 0, stream,
                       q, k1, k2, v1, v2, zout, lseout);
}

// Round 3
// 78.202 us; speedup vs baseline: 3.5955x; 2.9457x over previous
//
#include <hip/hip_runtime.h>
#include <math.h>

// Trittention forward: B=2,H=8,S=192,D=64, fp32 in/out.
// scores[q,t,s] = sum_h q[h]*k1[t,h]*k2[s,h]  ==  (W @ k2^T) with W = q (.) k1
// softmax over flat (t,s); z = (sum_t At v1 + sum_s As v2)/suma via marginals.
// Round 3: fix round-2's scratch spill. launch_bounds(512,4) -> 128 VGPR cap
// (acc 72 + frags ~20 + addr fits); afr loaded per-i to cut live range.
// suma computed from the At marginal (drops 72 adds + 6 shfl per thread).

#define SS 192
#define DD 64
#define NT 512   // 8 waves: 2 (t) x 4 (s) wave grid

typedef __attribute__((ext_vector_type(8))) short bf16x8;
typedef __attribute__((ext_vector_type(4))) float f32x4;

static __device__ __forceinline__ unsigned short f2bf(float x) {
    union { float f; unsigned u; } v; v.f = x;
    unsigned u = v.u;
    return (unsigned short)((u + 0x7fffu + ((u >> 16) & 1u)) >> 16);  // RNE
}

__launch_bounds__(NT, 4)
__global__ void tritt_fwd(const float* __restrict__ qg,
                          const float* __restrict__ k1g,
                          const float* __restrict__ k2g,
                          const float* __restrict__ v1g,
                          const float* __restrict__ v2g,
                          float* __restrict__ zg,
                          float* __restrict__ lseg) {
    // bf16 tiles, row = 64 bf16 = 8 chunks of 16B; chunk c stored at c^(r&7).
    __shared__ uint4 wl[SS * 8];
    __shared__ uint4 k2l[SS * 8];
    __shared__ float At[SS];
    __shared__ float As[SS];
    __shared__ float zsh[DD];
    __shared__ float redm[8];
    __shared__ float sum_sh;

    const int tid = threadIdx.x;
    const int bid = blockIdx.x;           // (b*H + n)*S + q
    const int head = bid / SS;
    const size_t hb = (size_t)head * SS * DD;

    if (tid < SS) At[tid] = 0.f;
    else if (tid < 2 * SS) As[tid - SS] = 0.f;
    else if (tid < 2 * SS + DD) zsh[tid - 2 * SS] = 0.f;

    // ---- stage W = q*k1 and k2 into LDS as bf16 (swizzled 16B chunks) ----
    const float4* k1v = (const float4*)(k1g + hb);
    const float4* k2v = (const float4*)(k2g + hb);
    const float4* qv  = (const float4*)(qg + (size_t)bid * DD);
    #pragma unroll
    for (int it = 0; it < (SS * 8) / NT; ++it) {   // 3 iters
        int f8 = tid + it * NT;            // 16B-chunk id, 0..1535
        int r = f8 >> 3;                   // row
        int c = f8 & 7;                    // chunk within row
        int idx = r * 8 + (c ^ (r & 7));
        float4 a0 = k1v[2 * f8], a1 = k1v[2 * f8 + 1];
        float4 q0 = qv[2 * c],   q1 = qv[2 * c + 1];
        uint4 w;
        w.x = (unsigned)f2bf(a0.x * q0.x) | ((unsigned)f2bf(a0.y * q0.y) << 16);
        w.y = (unsigned)f2bf(a0.z * q0.z) | ((unsigned)f2bf(a0.w * q0.w) << 16);
        w.z = (unsigned)f2bf(a1.x * q1.x) | ((unsigned)f2bf(a1.y * q1.y) << 16);
        w.w = (unsigned)f2bf(a1.z * q1.z) | ((unsigned)f2bf(a1.w * q1.w) << 16);
        wl[idx] = w;
        float4 b0 = k2v[2 * f8], b1 = k2v[2 * f8 + 1];
        uint4 kk;
        kk.x = (unsigned)f2bf(b0.x) | ((unsigned)f2bf(b0.y) << 16);
        kk.y = (unsigned)f2bf(b0.z) | ((unsigned)f2bf(b0.w) << 16);
        kk.z = (unsigned)f2bf(b1.x) | ((unsigned)f2bf(b1.y) << 16);
        kk.w = (unsigned)f2bf(b1.z) | ((unsigned)f2bf(b1.w) << 16);
        k2l[idx] = kk;
    }
    __syncthreads();

    // ---- score GEMM on MFMA: 192x192, K=64. Wave (wt,ws) owns 96x48. ----
    const int lane = tid & 63;
    const int wid  = tid >> 6;
    const int wt   = wid >> 2;            // 0..1
    const int ws   = wid & 3;             // 0..3
    const int lrow = lane & 15;
    const int lk   = lane >> 4;           // 0..3 (k-group)

    f32x4 acc[6][3];
    #pragma unroll
    for (int i = 0; i < 6; ++i)
        #pragma unroll
        for (int j = 0; j < 3; ++j)
            acc[i][j] = (f32x4){0.f, 0.f, 0.f, 0.f};

    #pragma unroll
    for (int ks = 0; ks < 2; ++ks) {
        bf16x8 bfr[3];
        #pragma unroll
        for (int j = 0; j < 3; ++j) {
            int srow = ws * 48 + j * 16 + lrow;
            bfr[j] = *(const bf16x8*)&k2l[srow * 8 + ((ks * 4 + lk) ^ (srow & 7))];
        }
        #pragma unroll
        for (int i = 0; i < 6; ++i) {
            int trow = wt * 96 + i * 16 + lrow;
            bf16x8 afr = *(const bf16x8*)&wl[trow * 8 + ((ks * 4 + lk) ^ (trow & 7))];
            #pragma unroll
            for (int j = 0; j < 3; ++j)
                acc[i][j] = __builtin_amdgcn_mfma_f32_16x16x32_bf16(
                    afr, bfr[j], acc[i][j], 0, 0, 0);
        }
    }
    // D mapping: col(s) = lane&15, row(t) = (lane>>4)*4 + reg.

    // ---- exact block max (all 36864 scores live in registers) ----
    float lm = -1e30f;
    #pragma unroll
    for (int i = 0; i < 6; ++i)
        #pragma unroll
        for (int j = 0; j < 3; ++j)
            #pragma unroll
            for (int r = 0; r < 4; ++r) lm = fmaxf(lm, acc[i][j][r]);
    #pragma unroll
    for (int off = 1; off < 64; off <<= 1)
        lm = fmaxf(lm, __shfl_xor(lm, off, 64));
    if (lane == 0) redm[wid] = lm;
    __syncthreads();
    if (tid == 0) {
        float m = redm[0];
        #pragma unroll
        for (int w = 1; w < 8; ++w) m = fmaxf(m, redm[w]);
        redm[0] = m;
    }
    __syncthreads();
    const float bm = redm[0];

    // ---- exp + marginals (suma derived from At afterwards) ----
    float colp[3] = {0.f, 0.f, 0.f};
    #pragma unroll
    for (int i = 0; i < 6; ++i) {
        float rs[4] = {0.f, 0.f, 0.f, 0.f};
        #pragma unroll
        for (int j = 0; j < 3; ++j)
            #pragma unroll
            for (int r = 0; r < 4; ++r) {
                float p = __expf(acc[i][j][r] - bm);
                rs[r] += p;
                colp[j] += p;
            }
        #pragma unroll
        for (int r = 0; r < 4; ++r) {
            float v = rs[r];
            v += __shfl_xor(v, 1, 64);
            v += __shfl_xor(v, 2, 64);
            v += __shfl_xor(v, 4, 64);
            v += __shfl_xor(v, 8, 64);
            if (lrow == 0)
                atomicAdd(&At[wt * 96 + i * 16 + lk * 4 + r], v);
        }
    }
    #pragma unroll
    for (int j = 0; j < 3; ++j) {
        float v = colp[j];
        v += __shfl_xor(v, 16, 64);
        v += __shfl_xor(v, 32, 64);
        if (lane < 16)
            atomicAdd(&As[ws * 48 + j * 16 + lane], v);
    }
    __syncthreads();

    // suma = sum of At (wave 0 only; 192 entries, 3 per lane)
    if (wid == 0) {
        float s = At[lane] + At[lane + 64] + At[lane + 128];
        #pragma unroll
        for (int off = 1; off < 64; off <<= 1)
            s += __shfl_xor(s, off, 64);
        if (lane == 0) sum_sh = s;
    }
    __syncthreads();

    // ---- epilogue: z[d] = (sum_t At v1 + sum_s As v2) / suma ----
    const int d = tid & 63;
    const int g = tid >> 6;               // 0..7, each covers 24 rows
    const float* v1p = v1g + hb;
    const float* v2p = v2g + hb;
    float zp = 0.f;
    #pragma unroll
    for (int r = 0; r < 24; ++r) {
        int t = g * 24 + r;
        zp = fmaf(At[t], v1p[t * DD + d], zp);
        zp = fmaf(As[t], v2p[t * DD + d], zp);
    }
    atomicAdd(&zsh[d], zp);
    __syncthreads();

    const float suma = sum_sh;
    if (tid < DD) zg[(size_t)bid * DD + tid] = zsh[tid] / suma;
    if (tid == 0) lseg[bid] = bm + logf(suma);
}

extern "C" void kernel_launch(void* const* d_in, const int* in_sizes, int n_in,
                              void* d_out, int out_size, void* d_ws, size_t ws_size,
                              hipStream_t stream) {
    const float* q  = (const float*)d_in[0];
    const float* k1 = (const float*)d_in[1];
    const float* k2 = (const float*)d_in[2];
    const float* v1 = (const float*)d_in[3];
    const float* v2 = (const float*)d_in[4];
    float* out = (float*)d_out;

    const int nq = in_sizes[0] / DD;      // B*H*S = 3072
    float* zout   = out;
    float* lseout = out + (size_t)nq * DD;

    dim3 grid(nq), block(NT);
    hipLaunchKernelGGL(tritt_fwd, grid, block, 0, stream,
                       q, k1, k2, v1, v2, zout, lseout);
}